// Round 1
// baseline (666.260 us; speedup 1.0000x reference)
//
#include <hip/hip_runtime.h>
#include <hip/hip_bf16.h>

#define S_LEN 2048
#define BATCH 8
#define HID   1024
#define NP    3072      // permuted gate dim: i,g,o only (f is dead in reference)
#define MROWS 16384     // S*B

using bf16x8 = __attribute__((ext_vector_type(8))) short;
using f32x4  = __attribute__((ext_vector_type(4))) float;

__device__ __forceinline__ unsigned short f2b(float f) {
  unsigned int u = __builtin_bit_cast(unsigned int, f);
  u += 0x7fffu + ((u >> 16) & 1u);   // RNE
  return (unsigned short)(u >> 16);
}

__device__ __forceinline__ void load_lds16(const void* g, void* l) {
  __builtin_amdgcn_global_load_lds(
      (const __attribute__((address_space(1))) void*)g,
      (__attribute__((address_space(3))) void*)(unsigned int)(unsigned long long)l,
      16, 0, 0);
}

// ---- fp32 -> bf16 convert (vectorized float4 -> ushort4) ----
__global__ void cvt_f32_bf16(const float* __restrict__ in,
                             unsigned short* __restrict__ out, int n4) {
  int i = blockIdx.x * blockDim.x + threadIdx.x;
  if (i >= n4) return;
  const float4 v = reinterpret_cast<const float4*>(in)[i];
  ushort4 u;
  u.x = f2b(v.x); u.y = f2b(v.y); u.z = f2b(v.z); u.w = f2b(v.w);
  reinterpret_cast<ushort4*>(out)[i] = u;
}

// ---- weight permute+convert: Wp[n'][k], n' = chunk*48 + gate3*16 + hl,
//      gate3 {0:i,1:g,2:o} -> orig rows {0,2,3}*1024 + chunk*16 + hl ----
__global__ void permute_w(const float* __restrict__ W,
                          unsigned short* __restrict__ Wp, int K) {
  long i = ((long)blockIdx.x * blockDim.x + threadIdx.x) * 4;
  int np = (int)(i / K);
  if (np >= NP) return;
  int k0 = (int)(i % K);
  int chunk = np / 48, rem = np % 48;
  int g3 = rem >> 4, hl = rem & 15;
  int og = (g3 == 0) ? 0 : (g3 == 1) ? 2 : 3;
  int n  = og * 1024 + chunk * 16 + hl;
  const float4 v = *reinterpret_cast<const float4*>(W + (long)n * K + k0);
  ushort4 u;
  u.x = f2b(v.x); u.y = f2b(v.y); u.z = f2b(v.z); u.w = f2b(v.w);
  *reinterpret_cast<ushort4*>(Wp + i) = u;
}

__global__ void permute_b(const float* __restrict__ b, float* __restrict__ bp) {
  int np = blockIdx.x * blockDim.x + threadIdx.x;
  if (np >= NP) return;
  int chunk = np / 48, rem = np % 48;
  int g3 = rem >> 4, hl = rem & 15;
  int og = (g3 == 0) ? 0 : (g3 == 1) ? 2 : 3;
  bp[np] = b[og * 1024 + chunk * 16 + hl];
}

// ---- fused GEMM + gates. C = A[M,K] * Wp[NP,K]^T, tile 128x96, BK=64,
//      4 waves (2x2), wave tile 64x48 = 4 m-frags x 3 n-frags (i,g,o). ----
template <int MODE>  // 0: layer0 (bf16 out), 1: layer1 (fp32 out to d_out)
__global__ void __launch_bounds__(256, 2)
lstm_gemm(const unsigned short* __restrict__ A,
          const unsigned short* __restrict__ WpF,
          const unsigned short* __restrict__ WpB,
          const float* __restrict__ bpF, const float* __restrict__ bpB,
          int K,
          unsigned short* __restrict__ out_bf, float* __restrict__ out_f,
          float* __restrict__ hn, float* __restrict__ cn) {
  const int dir = blockIdx.z;
  const unsigned short* __restrict__ Wp = dir ? WpB : WpF;
  const float* __restrict__ bp = dir ? bpB : bpF;
  const int bm = blockIdx.y;
  const int bn = blockIdx.x;

  __shared__ __align__(16) unsigned short Abuf[128 * 64];
  __shared__ __align__(16) unsigned short Bbuf[96 * 64];

  const int tid  = threadIdx.x;
  const int wid  = tid >> 6;
  const int lane = tid & 63;
  const int wm   = wid >> 1;   // 0..1
  const int wn   = wid & 1;    // 0..1

  f32x4 acc[4][3];
  const f32x4 zero = {0.f, 0.f, 0.f, 0.f};
#pragma unroll
  for (int i = 0; i < 4; ++i)
#pragma unroll
    for (int j = 0; j < 3; ++j) acc[i][j] = zero;

  const long a_base_row = (long)bm * 128;
  const long b_base_row = (long)bn * 96;
  const int  kt_count   = K >> 6;
  const long krow_bytes = (long)K * 2;

  for (int kt = 0; kt < kt_count; ++kt) {
    const long kbyte = (long)kt * 128;  // 64 bf16 = 128 B
    // stage A: 128 rows x 128 B; 16 wave-slices of 1024 B (8 rows each)
#pragma unroll
    for (int it = 0; it < 4; ++it) {
      const int base = (it * 4 + wid) * 1024;
      const int p    = base + lane * 16;
      const int row  = p >> 7;
      const int colb = (p & 127) ^ ((row & 7) << 4);  // pre-swizzled source
      const char* src = (const char*)A + (a_base_row + row) * krow_bytes + kbyte + colb;
      load_lds16(src, (char*)Abuf + base);
    }
    // stage B: 96 rows; 12 wave-slices
#pragma unroll
    for (int it = 0; it < 3; ++it) {
      const int base = (it * 4 + wid) * 1024;
      const int p    = base + lane * 16;
      const int row  = p >> 7;
      const int colb = (p & 127) ^ ((row & 7) << 4);
      const char* src = (const char*)Wp + (b_base_row + row) * krow_bytes + kbyte + colb;
      load_lds16(src, (char*)Bbuf + base);
    }
    asm volatile("s_waitcnt vmcnt(0)" ::: "memory");
    __syncthreads();

#pragma unroll
    for (int kb = 0; kb < 2; ++kb) {
      bf16x8 af[4];
      bf16x8 bfr[3];
#pragma unroll
      for (int mf = 0; mf < 4; ++mf) {
        const int row = wm * 64 + mf * 16 + (lane & 15);
        int byte = row * 128 + kb * 64 + ((lane >> 4) * 16);
        byte ^= (row & 7) << 4;  // swizzled read
        af[mf] = *(const bf16x8*)((const char*)Abuf + byte);
      }
#pragma unroll
      for (int nf = 0; nf < 3; ++nf) {
        const int row = wn * 48 + nf * 16 + (lane & 15);
        int byte = row * 128 + kb * 64 + ((lane >> 4) * 16);
        byte ^= (row & 7) << 4;
        bfr[nf] = *(const bf16x8*)((const char*)Bbuf + byte);
      }
#pragma unroll
      for (int mf = 0; mf < 4; ++mf)
#pragma unroll
        for (int nf = 0; nf < 3; ++nf)
          acc[mf][nf] = __builtin_amdgcn_mfma_f32_16x16x32_bf16(
              af[mf], bfr[nf], acc[mf][nf], 0, 0, 0);
    }
    __syncthreads();
  }

  // ---- epilogue: gates -> h (and h_n/c_n rows) ----
  const int col    = lane & 15;
  const int chunk  = bn * 2 + wn;       // 0..63
  const int h      = chunk * 16 + col;  // 0..1023
  const int outcol = dir * HID + h;
  const float bi = bp[chunk * 48 + col];
  const float bg = bp[chunk * 48 + 16 + col];
  const float bo = bp[chunk * 48 + 32 + col];
  const int Lidx = MODE * 2 + dir;

#pragma unroll
  for (int mf = 0; mf < 4; ++mf) {
#pragma unroll
    for (int r = 0; r < 4; ++r) {
      const int m = bm * 128 + wm * 64 + mf * 16 + (lane >> 4) * 4 + r;
      const float iv = acc[mf][0][r] + bi;
      const float gv = acc[mf][1][r] + bg;
      const float ov = acc[mf][2][r] + bo;
      const float is = 1.f / (1.f + __expf(-iv));
      const float gt = tanhf(gv);
      const float os = 1.f / (1.f + __expf(-ov));
      const float c  = is * gt;
      const float hv = os * tanhf(c);
      if (MODE == 0) {
        out_bf[(long)m * 2048 + outcol] = f2b(hv);
      } else {
        out_f[(long)m * 2048 + outcol] = hv;
      }
      const bool wst = (dir == 0) ? (m >= (S_LEN - 1) * BATCH) : (m < BATCH);
      if (wst) {
        const int b = (dir == 0) ? (m - (S_LEN - 1) * BATCH) : m;
        hn[((long)Lidx * BATCH + b) * HID + h] = hv;
        cn[((long)Lidx * BATCH + b) * HID + h] = c;
      }
    }
  }
}

extern "C" void kernel_launch(void* const* d_in, const int* in_sizes, int n_in,
                              void* d_out, int out_size, void* d_ws, size_t ws_size,
                              hipStream_t stream) {
  const float* x    = (const float*)d_in[0];
  const float* W_f0 = (const float*)d_in[1];
  const float* b_f0 = (const float*)d_in[2];
  const float* W_b0 = (const float*)d_in[3];
  const float* b_b0 = (const float*)d_in[4];
  const float* W_f1 = (const float*)d_in[5];
  const float* b_f1 = (const float*)d_in[6];
  const float* W_b1 = (const float*)d_in[7];
  const float* b_b1 = (const float*)d_in[8];

  float* out = (float*)d_out;
  float* hn  = out + (long)MROWS * 2048;
  float* cn  = hn + 4 * BATCH * HID;

  unsigned short* x_bf  = (unsigned short*)d_ws;
  unsigned short* out1  = x_bf + (long)MROWS * 1024;
  unsigned short* wp_f0 = out1 + (long)MROWS * 2048;
  unsigned short* wp_b0 = wp_f0 + (long)NP * 1024;
  unsigned short* wp_f1 = wp_b0 + (long)NP * 1024;
  unsigned short* wp_b1 = wp_f1 + (long)NP * 2048;
  float* bp_f0 = (float*)(wp_b1 + (long)NP * 2048);
  float* bp_b0 = bp_f0 + NP;
  float* bp_f1 = bp_b0 + NP;
  float* bp_b1 = bp_f1 + NP;

  cvt_f32_bf16<<<16384, 256, 0, stream>>>(x, x_bf, MROWS * 1024 / 4);
  permute_w<<<3072, 256, 0, stream>>>(W_f0, wp_f0, 1024);
  permute_w<<<3072, 256, 0, stream>>>(W_b0, wp_b0, 1024);
  permute_w<<<6144, 256, 0, stream>>>(W_f1, wp_f1, 2048);
  permute_w<<<6144, 256, 0, stream>>>(W_b1, wp_b1, 2048);
  permute_b<<<12, 256, 0, stream>>>(b_f0, bp_f0);
  permute_b<<<12, 256, 0, stream>>>(b_b0, bp_b0);
  permute_b<<<12, 256, 0, stream>>>(b_f1, bp_f1);
  permute_b<<<12, 256, 0, stream>>>(b_b1, bp_b1);

  dim3 grid(NP / 96, MROWS / 128, 2);
  lstm_gemm<0><<<grid, 256, 0, stream>>>(x_bf, wp_f0, wp_b0, bp_f0, bp_b0, 1024,
                                         out1, nullptr, hn, cn);
  lstm_gemm<1><<<grid, 256, 0, stream>>>(out1, wp_f1, wp_b1, bp_f1, bp_b1, 2048,
                                         nullptr, out, hn, cn);
}